// Round 1
// baseline (5841.328 us; speedup 1.0000x reference)
//
#include <hip/hip_runtime.h>

#define D 128
#define NCLS 64

// ---- small helpers -------------------------------------------------------

__global__ __launch_bounds__(256) void k_transpose(const float* __restrict__ A,
                                                   float* __restrict__ AT, int R, int C) {
  int t = blockIdx.x * 256 + threadIdx.x;
  if (t < R * C) {
    int r = t / C, c = t % C;
    AT[c * R + r] = A[t];
  }
}

__global__ __launch_bounds__(256) void k_degree(const int* __restrict__ dst,
                                                float* __restrict__ deg, int E) {
  int e = blockIdx.x * 256 + threadIdx.x;
  if (e < E) atomicAdd(&deg[dst[e]], 1.0f);
}

__global__ __launch_bounds__(256) void k_invdeg(float* deg, int N) {
  int i = blockIdx.x * 256 + threadIdx.x;
  if (i < N) deg[i] = 1.0f / fmaxf(deg[i], 1.0f);
}

// ---- mean-aggregation numerator: agg[dst] += h[src] ----------------------
// one thread per (edge, 4 features); 32 threads cover one edge's 128 feats

__global__ __launch_bounds__(256) void k_aggregate(const float* __restrict__ h,
                                                   const int* __restrict__ src,
                                                   const int* __restrict__ dst,
                                                   float* __restrict__ agg, int E) {
  int t = blockIdx.x * 256 + threadIdx.x;
  int e = t >> 5;
  if (e >= E) return;
  int f = (t & 31) << 2;
  int s = src[e], d = dst[e];
  const float4 v = *reinterpret_cast<const float4*>(h + (size_t)s * D + f);
  float* o = agg + (size_t)d * D + f;
  atomicAdd(o + 0, v.x);
  atomicAdd(o + 1, v.y);
  atomicAdd(o + 2, v.z);
  atomicAdd(o + 3, v.w);
}

// ---- out[row][col] = relu(bias[col] + scale[row] * sum_k in[row][k]*WT[k][col])
// WT is [k][col] 128x128 staged in LDS (64 KB). Block=256: 8 rows/iter,
// thread = (row tid>>5, 4 cols at (tid&31)*4). Grid-stride over rows.

__global__ __launch_bounds__(256) void k_gemm_relu(const float* __restrict__ in,
                                                   const float* __restrict__ scale,
                                                   const float* __restrict__ WT,
                                                   const float* __restrict__ bias,
                                                   float* __restrict__ out, int N) {
  __shared__ float Ws[D * D];  // 65536 B exactly
  for (int i = threadIdx.x * 4; i < D * D; i += 256 * 4)
    *reinterpret_cast<float4*>(Ws + i) = *reinterpret_cast<const float4*>(WT + i);
  __syncthreads();
  const int rl = threadIdx.x >> 5;
  const int cg = (threadIdx.x & 31) << 2;
  const float4 bb = *reinterpret_cast<const float4*>(bias + cg);
  for (int base = blockIdx.x * 8; base < N; base += gridDim.x * 8) {
    const int row = base + rl;
    const float* __restrict__ ir = in + (size_t)row * D;
    const float sc = scale[row];
    float ax = 0.f, ay = 0.f, az = 0.f, aw = 0.f;
#pragma unroll 8
    for (int k = 0; k < D; ++k) {
      const float a = ir[k];
      const float4 w = *reinterpret_cast<const float4*>(Ws + k * D + cg);
      ax += a * w.x;
      ay += a * w.y;
      az += a * w.z;
      aw += a * w.w;
    }
    float4 r;
    r.x = fmaxf(bb.x + sc * ax, 0.f);
    r.y = fmaxf(bb.y + sc * ay, 0.f);
    r.z = fmaxf(bb.z + sc * az, 0.f);
    r.w = fmaxf(bb.w + sc * aw, 0.f);
    *reinterpret_cast<float4*>(out + (size_t)row * D + cg) = r;
  }
}

// ---- logits[row][c] = bl[c] + sum_k cat(h1,h2)[row][k] * WlT[k][c] -------
// WlT is [k=256][c=64] staged in LDS (64 KB). 16 rows/iter, thread =
// (row tid>>4, 4 cols at (tid&15)*4).

__global__ __launch_bounds__(256) void k_logits(const float* __restrict__ h1,
                                                const float* __restrict__ h2,
                                                const float* __restrict__ WlT,
                                                const float* __restrict__ bias,
                                                float* __restrict__ out, int N) {
  __shared__ float Ws[2 * D * NCLS];  // 65536 B exactly
  for (int i = threadIdx.x * 4; i < 2 * D * NCLS; i += 256 * 4)
    *reinterpret_cast<float4*>(Ws + i) = *reinterpret_cast<const float4*>(WlT + i);
  __syncthreads();
  const int rl = threadIdx.x >> 4;
  const int cg = (threadIdx.x & 15) << 2;
  const float4 bb = *reinterpret_cast<const float4*>(bias + cg);
  for (int base = blockIdx.x * 16; base < N; base += gridDim.x * 16) {
    const int row = base + rl;
    const float* __restrict__ p1 = h1 + (size_t)row * D;
    const float* __restrict__ p2 = h2 + (size_t)row * D;
    float ax = 0.f, ay = 0.f, az = 0.f, aw = 0.f;
#pragma unroll 8
    for (int k = 0; k < D; ++k) {
      const float a = p1[k];
      const float4 w = *reinterpret_cast<const float4*>(Ws + k * NCLS + cg);
      ax += a * w.x; ay += a * w.y; az += a * w.z; aw += a * w.w;
    }
#pragma unroll 8
    for (int k = 0; k < D; ++k) {
      const float a = p2[k];
      const float4 w = *reinterpret_cast<const float4*>(Ws + (D + k) * NCLS + cg);
      ax += a * w.x; ay += a * w.y; az += a * w.z; aw += a * w.w;
    }
    float4 r;
    r.x = bb.x + ax;
    r.y = bb.y + ay;
    r.z = bb.z + az;
    r.w = bb.w + aw;
    *reinterpret_cast<float4*>(out + (size_t)row * NCLS + cg) = r;
  }
}

// ---- in-place log_softmax over 64 classes: one wave per node -------------

__global__ __launch_bounds__(256) void k_logsoftmax(float* __restrict__ out, int N) {
  int gid = blockIdx.x * 256 + threadIdx.x;
  int node = gid >> 6;
  int lane = threadIdx.x & 63;
  if (node >= N) return;
  float v = out[(size_t)node * NCLS + lane];
  float m = v;
#pragma unroll
  for (int off = 32; off > 0; off >>= 1) m = fmaxf(m, __shfl_xor(m, off));
  float e = __expf(v - m);
#pragma unroll
  for (int off = 32; off > 0; off >>= 1) e += __shfl_xor(e, off);
  // e now holds sum of exps across the wave (all lanes)
  out[(size_t)node * NCLS + lane] = v - m - __logf(e);
}

// ---- driver --------------------------------------------------------------

extern "C" void kernel_launch(void* const* d_in, const int* in_sizes, int n_in,
                              void* d_out, int out_size, void* d_ws, size_t ws_size,
                              hipStream_t stream) {
  const float* feat = (const float*)d_in[0];
  const int* src = (const int*)d_in[1];
  const int* dst = (const int*)d_in[2];
  const float* W1 = (const float*)d_in[3];
  const float* b1 = (const float*)d_in[4];
  const float* W2 = (const float*)d_in[5];
  const float* b2 = (const float*)d_in[6];
  const float* Wl = (const float*)d_in[7];
  const float* bl = (const float*)d_in[8];
  float* out = (float*)d_out;

  const int N = in_sizes[0] / D;  // 100000
  const int E = in_sizes[1];      // 1600000

  // workspace layout (floats)
  float* ws = (float*)d_ws;
  float* inv = ws;                   // N      (deg, then inv_deg in place)
  float* agg = inv + N;              // N*128
  float* h1 = agg + (size_t)N * D;   // N*128
  float* h2 = h1 + (size_t)N * D;    // N*128
  float* W1T = h2 + (size_t)N * D;   // 16384
  float* W2T = W1T + D * D;          // 16384
  float* WlT = W2T + D * D;          // 16384

  // zero-init accumulators (ws is poisoned to 0xAA before every call)
  hipMemsetAsync(inv, 0, (size_t)N * sizeof(float), stream);
  hipMemsetAsync(agg, 0, (size_t)N * D * sizeof(float), stream);

  // transpose weights to [k][col]
  k_transpose<<<(D * D + 255) / 256, 256, 0, stream>>>(W1, W1T, D, D);
  k_transpose<<<(D * D + 255) / 256, 256, 0, stream>>>(W2, W2T, D, D);
  k_transpose<<<(NCLS * 2 * D + 255) / 256, 256, 0, stream>>>(Wl, WlT, NCLS, 2 * D);

  // degree -> inv_deg
  k_degree<<<(E + 255) / 256, 256, 0, stream>>>(dst, inv, E);
  k_invdeg<<<(N + 255) / 256, 256, 0, stream>>>(inv, N);

  // layer 1: agg = segsum(feat[src] on dst); h1 = relu(inv*agg @ W1T + b1)
  {
    long long threads = (long long)E * 32;
    int blocks = (int)((threads + 255) / 256);
    k_aggregate<<<blocks, 256, 0, stream>>>(feat, src, dst, agg, E);
  }
  k_gemm_relu<<<512, 256, 0, stream>>>(agg, inv, W1T, b1, h1, N);

  // layer 2
  hipMemsetAsync(agg, 0, (size_t)N * D * sizeof(float), stream);
  {
    long long threads = (long long)E * 32;
    int blocks = (int)((threads + 255) / 256);
    k_aggregate<<<blocks, 256, 0, stream>>>(h1, src, dst, agg, E);
  }
  k_gemm_relu<<<512, 256, 0, stream>>>(agg, inv, W2T, b2, h2, N);

  // logits + log_softmax (in place on d_out)
  k_logits<<<512, 256, 0, stream>>>(h1, h2, WlT, bl, out, N);
  k_logsoftmax<<<((size_t)N * 64 + 255) / 256, 256, 0, stream>>>(out, N);
}

// Round 2
// 908.594 us; speedup vs baseline: 6.4290x; 6.4290x over previous
//
#include <hip/hip_runtime.h>

#define D 128
#define NCLS 64

// ---- small helpers -------------------------------------------------------

__global__ __launch_bounds__(256) void k_transpose(const float* __restrict__ A,
                                                   float* __restrict__ AT, int R, int C) {
  int t = blockIdx.x * 256 + threadIdx.x;
  if (t < R * C) {
    int r = t / C, c = t % C;
    AT[c * R + r] = A[t];
  }
}

// ---- CSR build: histogram -> exclusive scan -> scatter -------------------

__global__ __launch_bounds__(256) void k_hist(const int* __restrict__ dst,
                                              int* __restrict__ cnt, int E) {
  int e = blockIdx.x * 256 + threadIdx.x;
  if (e < E) atomicAdd(&cnt[dst[e]], 1);
}

__global__ __launch_bounds__(256) void k_invdeg(const int* __restrict__ cnt,
                                                float* __restrict__ inv, int N) {
  int i = blockIdx.x * 256 + threadIdx.x;
  if (i < N) inv[i] = 1.0f / fmaxf((float)cnt[i], 1.0f);
}

// scan1: each block scans 1024 counts (4/thread), writes local-exclusive + block total
__global__ __launch_bounds__(256) void k_scan1(const int* __restrict__ cnt,
                                               int* __restrict__ loc,
                                               int* __restrict__ part, int N) {
  __shared__ int sm[256];
  const int base = blockIdx.x * 1024 + threadIdx.x * 4;
  int v0 = 0, v1 = 0, v2 = 0, v3 = 0;
  if (base + 0 < N) v0 = cnt[base + 0];
  if (base + 1 < N) v1 = cnt[base + 1];
  if (base + 2 < N) v2 = cnt[base + 2];
  if (base + 3 < N) v3 = cnt[base + 3];
  const int ts = v0 + v1 + v2 + v3;
  sm[threadIdx.x] = ts;
  __syncthreads();
  for (int off = 1; off < 256; off <<= 1) {
    int t = (threadIdx.x >= off) ? sm[threadIdx.x - off] : 0;
    __syncthreads();
    sm[threadIdx.x] += t;
    __syncthreads();
  }
  const int excl = sm[threadIdx.x] - ts;
  if (base + 0 < N) loc[base + 0] = excl;
  if (base + 1 < N) loc[base + 1] = excl + v0;
  if (base + 2 < N) loc[base + 2] = excl + v0 + v1;
  if (base + 3 < N) loc[base + 3] = excl + v0 + v1 + v2;
  if (threadIdx.x == 255) part[blockIdx.x] = sm[255];
}

// scan2: one block, exclusive scan of P (<=128) block totals in place
__global__ __launch_bounds__(128) void k_scan2(int* part, int P) {
  __shared__ int sm[128];
  int v = (threadIdx.x < P) ? part[threadIdx.x] : 0;
  sm[threadIdx.x] = v;
  __syncthreads();
  for (int off = 1; off < 128; off <<= 1) {
    int t = (threadIdx.x >= off) ? sm[threadIdx.x - off] : 0;
    __syncthreads();
    sm[threadIdx.x] += t;
    __syncthreads();
  }
  if (threadIdx.x < P) part[threadIdx.x] = sm[threadIdx.x] - v;
}

// scan3: row_ptr = loc + part[block]; cursor copy; row_ptr[N]=E
__global__ __launch_bounds__(256) void k_scan3(const int* __restrict__ loc,
                                               const int* __restrict__ part,
                                               int* __restrict__ row_ptr,
                                               int* __restrict__ cursor, int N, int E) {
  const int base = blockIdx.x * 1024 + threadIdx.x * 4;
  const int off = part[blockIdx.x];
#pragma unroll
  for (int j = 0; j < 4; ++j) {
    int i = base + j;
    if (i < N) {
      int v = loc[i] + off;
      row_ptr[i] = v;
      cursor[i] = v;
    }
  }
  if (blockIdx.x == 0 && threadIdx.x == 0) row_ptr[N] = E;
}

__global__ __launch_bounds__(256) void k_scatter(const int* __restrict__ src,
                                                 const int* __restrict__ dst,
                                                 int* __restrict__ cursor,
                                                 int* __restrict__ esrc, int E) {
  int e = blockIdx.x * 256 + threadIdx.x;
  if (e < E) {
    int p = atomicAdd(&cursor[dst[e]], 1);
    esrc[p] = src[e];
  }
}

// ---- mean aggregation via CSR gather: one wave per node ------------------
// lane handles 2 features (float2); per edge: 64 lanes read one contiguous
// 512 B row of h. No atomics; output written exactly once (mean folded in).

__global__ __launch_bounds__(256) void k_gather_mean(const float* __restrict__ h,
                                                     const int* __restrict__ row_ptr,
                                                     const int* __restrict__ esrc,
                                                     const float* __restrict__ inv,
                                                     float* __restrict__ out, int N) {
  const int node = blockIdx.x * 4 + (threadIdx.x >> 6);
  if (node >= N) return;
  const int lane = threadIdx.x & 63;
  const int beg = row_ptr[node];
  const int end = row_ptr[node + 1];
  float ax = 0.f, ay = 0.f;
  int e = beg;
  for (; e + 1 < end; e += 2) {
    const int s0 = esrc[e];
    const int s1 = esrc[e + 1];
    const float2 v0 = *reinterpret_cast<const float2*>(h + (size_t)s0 * D + lane * 2);
    const float2 v1 = *reinterpret_cast<const float2*>(h + (size_t)s1 * D + lane * 2);
    ax += v0.x + v1.x;
    ay += v0.y + v1.y;
  }
  if (e < end) {
    const int s0 = esrc[e];
    const float2 v0 = *reinterpret_cast<const float2*>(h + (size_t)s0 * D + lane * 2);
    ax += v0.x;
    ay += v0.y;
  }
  const float iv = inv[node];
  float2 r;
  r.x = ax * iv;
  r.y = ay * iv;
  *reinterpret_cast<float2*>(out + (size_t)node * D + lane * 2) = r;
}

// ---- out[row][col] = relu(bias[col] + sum_k in[row][k]*WT[k][col]) -------
// WT is [k][col] 128x128 staged in LDS (64 KB). Block=256: 8 rows/iter,
// thread = (row tid>>5, 4 cols at (tid&31)*4). Grid-stride over rows.

__global__ __launch_bounds__(256) void k_gemm_relu(const float* __restrict__ in,
                                                   const float* __restrict__ WT,
                                                   const float* __restrict__ bias,
                                                   float* __restrict__ out, int N) {
  __shared__ float Ws[D * D];  // 65536 B exactly
  for (int i = threadIdx.x * 4; i < D * D; i += 256 * 4)
    *reinterpret_cast<float4*>(Ws + i) = *reinterpret_cast<const float4*>(WT + i);
  __syncthreads();
  const int rl = threadIdx.x >> 5;
  const int cg = (threadIdx.x & 31) << 2;
  const float4 bb = *reinterpret_cast<const float4*>(bias + cg);
  for (int base = blockIdx.x * 8; base < N; base += gridDim.x * 8) {
    const int row = base + rl;
    const float* __restrict__ ir = in + (size_t)row * D;
    float ax = 0.f, ay = 0.f, az = 0.f, aw = 0.f;
#pragma unroll 8
    for (int k = 0; k < D; ++k) {
      const float a = ir[k];
      const float4 w = *reinterpret_cast<const float4*>(Ws + k * D + cg);
      ax += a * w.x;
      ay += a * w.y;
      az += a * w.z;
      aw += a * w.w;
    }
    float4 r;
    r.x = fmaxf(bb.x + ax, 0.f);
    r.y = fmaxf(bb.y + ay, 0.f);
    r.z = fmaxf(bb.z + az, 0.f);
    r.w = fmaxf(bb.w + aw, 0.f);
    *reinterpret_cast<float4*>(out + (size_t)row * D + cg) = r;
  }
}

// ---- logits[row][c] = bl[c] + sum_k cat(h1,h2)[row][k] * WlT[k][c] -------

__global__ __launch_bounds__(256) void k_logits(const float* __restrict__ h1,
                                                const float* __restrict__ h2,
                                                const float* __restrict__ WlT,
                                                const float* __restrict__ bias,
                                                float* __restrict__ out, int N) {
  __shared__ float Ws[2 * D * NCLS];  // 65536 B exactly
  for (int i = threadIdx.x * 4; i < 2 * D * NCLS; i += 256 * 4)
    *reinterpret_cast<float4*>(Ws + i) = *reinterpret_cast<const float4*>(WlT + i);
  __syncthreads();
  const int rl = threadIdx.x >> 4;
  const int cg = (threadIdx.x & 15) << 2;
  const float4 bb = *reinterpret_cast<const float4*>(bias + cg);
  for (int base = blockIdx.x * 16; base < N; base += gridDim.x * 16) {
    const int row = base + rl;
    const float* __restrict__ p1 = h1 + (size_t)row * D;
    const float* __restrict__ p2 = h2 + (size_t)row * D;
    float ax = 0.f, ay = 0.f, az = 0.f, aw = 0.f;
#pragma unroll 8
    for (int k = 0; k < D; ++k) {
      const float a = p1[k];
      const float4 w = *reinterpret_cast<const float4*>(Ws + k * NCLS + cg);
      ax += a * w.x; ay += a * w.y; az += a * w.z; aw += a * w.w;
    }
#pragma unroll 8
    for (int k = 0; k < D; ++k) {
      const float a = p2[k];
      const float4 w = *reinterpret_cast<const float4*>(Ws + (D + k) * NCLS + cg);
      ax += a * w.x; ay += a * w.y; az += a * w.z; aw += a * w.w;
    }
    float4 r;
    r.x = bb.x + ax;
    r.y = bb.y + ay;
    r.z = bb.z + az;
    r.w = bb.w + aw;
    *reinterpret_cast<float4*>(out + (size_t)row * NCLS + cg) = r;
  }
}

// ---- in-place log_softmax over 64 classes: one wave per node -------------

__global__ __launch_bounds__(256) void k_logsoftmax(float* __restrict__ out, int N) {
  int gid = blockIdx.x * 256 + threadIdx.x;
  int node = gid >> 6;
  int lane = threadIdx.x & 63;
  if (node >= N) return;
  float v = out[(size_t)node * NCLS + lane];
  float m = v;
#pragma unroll
  for (int off = 32; off > 0; off >>= 1) m = fmaxf(m, __shfl_xor(m, off));
  float e = __expf(v - m);
#pragma unroll
  for (int off = 32; off > 0; off >>= 1) e += __shfl_xor(e, off);
  out[(size_t)node * NCLS + lane] = v - m - __logf(e);
}

// ---- driver --------------------------------------------------------------

extern "C" void kernel_launch(void* const* d_in, const int* in_sizes, int n_in,
                              void* d_out, int out_size, void* d_ws, size_t ws_size,
                              hipStream_t stream) {
  const float* feat = (const float*)d_in[0];
  const int* src = (const int*)d_in[1];
  const int* dst = (const int*)d_in[2];
  const float* W1 = (const float*)d_in[3];
  const float* b1 = (const float*)d_in[4];
  const float* W2 = (const float*)d_in[5];
  const float* b2 = (const float*)d_in[6];
  const float* Wl = (const float*)d_in[7];
  const float* bl = (const float*)d_in[8];
  float* out = (float*)d_out;

  const int N = in_sizes[0] / D;  // 100000
  const int E = in_sizes[1];      // 1600000

  // workspace layout
  float* ws = (float*)d_ws;
  float* inv = ws;                      // N
  float* agg = inv + N;                 // N*D
  float* h1 = agg + (size_t)N * D;      // N*D
  float* h2 = h1 + (size_t)N * D;       // N*D
  float* W1T = h2 + (size_t)N * D;      // D*D
  float* W2T = W1T + D * D;             // D*D
  float* WlT = W2T + D * D;             // 2*D*NCLS
  int* cnt = (int*)(WlT + 2 * D * NCLS);  // N
  int* loc = cnt + N;                   // N
  int* part = loc + N;                  // 128
  int* row_ptr = part + 128;            // N+1
  int* cursor = row_ptr + N + 1;        // N
  int* esrc = cursor + N;               // E

  const int scanBlocks = (N + 1023) / 1024;  // 98

  // zero-init degree counters (ws is poisoned to 0xAA before every call)
  hipMemsetAsync(cnt, 0, (size_t)N * sizeof(int), stream);

  // transpose weights to [k][col]
  k_transpose<<<(D * D + 255) / 256, 256, 0, stream>>>(W1, W1T, D, D);
  k_transpose<<<(D * D + 255) / 256, 256, 0, stream>>>(W2, W2T, D, D);
  k_transpose<<<(NCLS * 2 * D + 255) / 256, 256, 0, stream>>>(Wl, WlT, NCLS, 2 * D);

  // CSR build
  k_hist<<<(E + 255) / 256, 256, 0, stream>>>(dst, cnt, E);
  k_invdeg<<<(N + 255) / 256, 256, 0, stream>>>(cnt, inv, N);
  k_scan1<<<scanBlocks, 256, 0, stream>>>(cnt, loc, part, N);
  k_scan2<<<1, 128, 0, stream>>>(part, scanBlocks);
  k_scan3<<<scanBlocks, 256, 0, stream>>>(loc, part, row_ptr, cursor, N, E);
  k_scatter<<<(E + 255) / 256, 256, 0, stream>>>(src, dst, cursor, esrc, E);

  const int gatherBlocks = (N + 3) / 4;

  // layer 1: agg = mean(feat[neigh]); h1 = relu(agg @ W1T + b1)
  k_gather_mean<<<gatherBlocks, 256, 0, stream>>>(feat, row_ptr, esrc, inv, agg, N);
  k_gemm_relu<<<512, 256, 0, stream>>>(agg, W1T, b1, h1, N);

  // layer 2
  k_gather_mean<<<gatherBlocks, 256, 0, stream>>>(h1, row_ptr, esrc, inv, agg, N);
  k_gemm_relu<<<512, 256, 0, stream>>>(agg, W2T, b2, h2, N);

  // logits + log_softmax (in place on d_out)
  k_logits<<<512, 256, 0, stream>>>(h1, h2, WlT, bl, out, N);
  k_logsoftmax<<<((size_t)N * 64 + 255) / 256, 256, 0, stream>>>(out, N);
}

// Round 3
// 602.158 us; speedup vs baseline: 9.7006x; 1.5089x over previous
//
#include <hip/hip_runtime.h>
#include <stdint.h>

#define D 128
#define NCLS 64

typedef __bf16 bf16x8 __attribute__((ext_vector_type(8)));
typedef float f32x4 __attribute__((ext_vector_type(4)));

union B8 { uint4 u; bf16x8 v; };

// ---- f32 -> bf16 bulk convert (8 elems/thread) ---------------------------

__global__ __launch_bounds__(256) void k_tobf16(const float* __restrict__ x,
                                                ushort* __restrict__ y, int n8) {
  int t = blockIdx.x * 256 + threadIdx.x;
  if (t >= n8) return;
  const float4 a = reinterpret_cast<const float4*>(x)[t * 2 + 0];
  const float4 b = reinterpret_cast<const float4*>(x)[t * 2 + 1];
  union { __bf16 h[8]; uint4 u; } p;
  p.h[0] = (__bf16)a.x; p.h[1] = (__bf16)a.y; p.h[2] = (__bf16)a.z; p.h[3] = (__bf16)a.w;
  p.h[4] = (__bf16)b.x; p.h[5] = (__bf16)b.y; p.h[6] = (__bf16)b.z; p.h[7] = (__bf16)b.w;
  reinterpret_cast<uint4*>(y)[t] = p.u;
}

// ---- CSR build: histogram -> exclusive scan -> scatter -------------------

__global__ __launch_bounds__(256) void k_hist(const int* __restrict__ dst,
                                              int* __restrict__ cnt, int E) {
  int e = blockIdx.x * 256 + threadIdx.x;
  if (e < E) atomicAdd(&cnt[dst[e]], 1);
}

__global__ __launch_bounds__(256) void k_invdeg(const int* __restrict__ cnt,
                                                float* __restrict__ inv, int N) {
  int i = blockIdx.x * 256 + threadIdx.x;
  if (i < N) inv[i] = 1.0f / fmaxf((float)cnt[i], 1.0f);
}

__global__ __launch_bounds__(256) void k_scan1(const int* __restrict__ cnt,
                                               int* __restrict__ loc,
                                               int* __restrict__ part, int N) {
  __shared__ int sm[256];
  const int base = blockIdx.x * 1024 + threadIdx.x * 4;
  int v0 = 0, v1 = 0, v2 = 0, v3 = 0;
  if (base + 0 < N) v0 = cnt[base + 0];
  if (base + 1 < N) v1 = cnt[base + 1];
  if (base + 2 < N) v2 = cnt[base + 2];
  if (base + 3 < N) v3 = cnt[base + 3];
  const int ts = v0 + v1 + v2 + v3;
  sm[threadIdx.x] = ts;
  __syncthreads();
  for (int off = 1; off < 256; off <<= 1) {
    int t = (threadIdx.x >= off) ? sm[threadIdx.x - off] : 0;
    __syncthreads();
    sm[threadIdx.x] += t;
    __syncthreads();
  }
  const int excl = sm[threadIdx.x] - ts;
  if (base + 0 < N) loc[base + 0] = excl;
  if (base + 1 < N) loc[base + 1] = excl + v0;
  if (base + 2 < N) loc[base + 2] = excl + v0 + v1;
  if (base + 3 < N) loc[base + 3] = excl + v0 + v1 + v2;
  if (threadIdx.x == 255) part[blockIdx.x] = sm[255];
}

__global__ __launch_bounds__(128) void k_scan2(int* part, int P) {
  __shared__ int sm[128];
  int v = (threadIdx.x < P) ? part[threadIdx.x] : 0;
  sm[threadIdx.x] = v;
  __syncthreads();
  for (int off = 1; off < 128; off <<= 1) {
    int t = (threadIdx.x >= off) ? sm[threadIdx.x - off] : 0;
    __syncthreads();
    sm[threadIdx.x] += t;
    __syncthreads();
  }
  if (threadIdx.x < P) part[threadIdx.x] = sm[threadIdx.x] - v;
}

__global__ __launch_bounds__(256) void k_scan3(const int* __restrict__ loc,
                                               const int* __restrict__ part,
                                               int* __restrict__ row_ptr,
                                               int* __restrict__ cursor, int N, int E) {
  const int base = blockIdx.x * 1024 + threadIdx.x * 4;
  const int off = part[blockIdx.x];
#pragma unroll
  for (int j = 0; j < 4; ++j) {
    int i = base + j;
    if (i < N) {
      int v = loc[i] + off;
      row_ptr[i] = v;
      cursor[i] = v;
    }
  }
  if (blockIdx.x == 0 && threadIdx.x == 0) row_ptr[N] = E;
}

__global__ __launch_bounds__(256) void k_scatter(const int* __restrict__ src,
                                                 const int* __restrict__ dst,
                                                 int* __restrict__ cursor,
                                                 int* __restrict__ esrc, int E) {
  int e = blockIdx.x * 256 + threadIdx.x;
  if (e < E) {
    int p = atomicAdd(&cursor[dst[e]], 1);
    esrc[p] = src[e];
  }
}

// ---- mean aggregation via CSR gather: one wave per node, bf16 ------------
// lane handles 2 bf16 (4 B); per edge the wave reads one contiguous 256 B row.

__global__ __launch_bounds__(256) void k_gather_mean(const ushort* __restrict__ h,
                                                     const int* __restrict__ row_ptr,
                                                     const int* __restrict__ esrc,
                                                     const float* __restrict__ inv,
                                                     ushort* __restrict__ out, int N) {
  const int node = blockIdx.x * 4 + (threadIdx.x >> 6);
  if (node >= N) return;
  const int lane = threadIdx.x & 63;
  const int beg = row_ptr[node];
  const int end = row_ptr[node + 1];
  float ax = 0.f, ay = 0.f;
  int e = beg;
  for (; e + 1 < end; e += 2) {
    const int s0 = esrc[e];
    const int s1 = esrc[e + 1];
    const unsigned int u0 = *reinterpret_cast<const unsigned int*>(h + (size_t)s0 * D + lane * 2);
    const unsigned int u1 = *reinterpret_cast<const unsigned int*>(h + (size_t)s1 * D + lane * 2);
    ax += __uint_as_float(u0 << 16) + __uint_as_float(u1 << 16);
    ay += __uint_as_float(u0 & 0xffff0000u) + __uint_as_float(u1 & 0xffff0000u);
  }
  if (e < end) {
    const unsigned int u0 = *reinterpret_cast<const unsigned int*>(h + (size_t)esrc[e] * D + lane * 2);
    ax += __uint_as_float(u0 << 16);
    ay += __uint_as_float(u0 & 0xffff0000u);
  }
  const float iv = inv[node];
  union { __bf16 b[2]; unsigned int u; } p;
  p.b[0] = (__bf16)(ax * iv);
  p.b[1] = (__bf16)(ay * iv);
  *reinterpret_cast<unsigned int*>(out + (size_t)node * D + lane * 2) = p.u;
}

// ---- MFMA GEMM: Hout = relu(A @ W^T + bias), A[N][128] bf16, W[128][128] f32
// Block = 4 waves; wave w covers cols [w*32, w*32+32) (2 n-tiles), grid-strides
// over 16-row M-tiles. W's [out][in] layout IS the B-fragment layout (lane
// holds col n=lane&15, 8 consecutive k) -> convert to bf16 regs once.

__global__ __launch_bounds__(256) void k_gemm_mfma(const ushort* __restrict__ A,
                                                   const float* __restrict__ W,
                                                   const float* __restrict__ bias,
                                                   ushort* __restrict__ Hout, int N) {
  const int wave = threadIdx.x >> 6;
  const int lane = threadIdx.x & 63;
  const int l15 = lane & 15;
  const int quad = lane >> 4;

  B8 bfrag[2][4];
  float bv[2];
#pragma unroll
  for (int t = 0; t < 2; ++t) {
    const int n = wave * 32 + t * 16 + l15;
    bv[t] = bias[n];
#pragma unroll
    for (int ks = 0; ks < 4; ++ks) {
      const float* wp = W + n * D + ks * 32 + quad * 8;
      const float4 w0 = *reinterpret_cast<const float4*>(wp);
      const float4 w1 = *reinterpret_cast<const float4*>(wp + 4);
      B8 b;
      b.v[0] = (__bf16)w0.x; b.v[1] = (__bf16)w0.y; b.v[2] = (__bf16)w0.z; b.v[3] = (__bf16)w0.w;
      b.v[4] = (__bf16)w1.x; b.v[5] = (__bf16)w1.y; b.v[6] = (__bf16)w1.z; b.v[7] = (__bf16)w1.w;
      bfrag[t][ks] = b;
    }
  }

  const int mtiles = N >> 4;  // N % 16 == 0 (100000 = 6250*16)
  for (int mt = blockIdx.x; mt < mtiles; mt += gridDim.x) {
    const ushort* ap = A + (size_t)(mt * 16 + l15) * D + quad * 8;
    B8 a0, a1, a2, a3;
    a0.u = *reinterpret_cast<const uint4*>(ap);
    a1.u = *reinterpret_cast<const uint4*>(ap + 32);
    a2.u = *reinterpret_cast<const uint4*>(ap + 64);
    a3.u = *reinterpret_cast<const uint4*>(ap + 96);
#pragma unroll
    for (int t = 0; t < 2; ++t) {
      f32x4 acc = {0.f, 0.f, 0.f, 0.f};
      acc = __builtin_amdgcn_mfma_f32_16x16x32_bf16(a0.v, bfrag[t][0].v, acc, 0, 0, 0);
      acc = __builtin_amdgcn_mfma_f32_16x16x32_bf16(a1.v, bfrag[t][1].v, acc, 0, 0, 0);
      acc = __builtin_amdgcn_mfma_f32_16x16x32_bf16(a2.v, bfrag[t][2].v, acc, 0, 0, 0);
      acc = __builtin_amdgcn_mfma_f32_16x16x32_bf16(a3.v, bfrag[t][3].v, acc, 0, 0, 0);
      const int col = wave * 32 + t * 16 + l15;
#pragma unroll
      for (int r = 0; r < 4; ++r) {
        const int row = mt * 16 + quad * 4 + r;
        const float v = fmaxf(acc[r] + bv[t], 0.f);
        union { __bf16 b; ushort s; } c;
        c.b = (__bf16)v;
        Hout[(size_t)row * D + col] = c.s;
      }
    }
  }
}

// ---- logits + log_softmax fused ------------------------------------------
// Block = 4 waves; wave w covers cols [w*16,w*16+16); K=256 (h1|h2).
// Wl[64][256] f32 -> bf16 B-frags in regs. After MFMA, 16x64 tile -> LDS ->
// per-row wave softmax -> coalesced f32 store.

__global__ __launch_bounds__(256) void k_logits_sm(const ushort* __restrict__ H1,
                                                   const ushort* __restrict__ H2,
                                                   const float* __restrict__ Wl,
                                                   const float* __restrict__ bl,
                                                   float* __restrict__ out, int N) {
  __shared__ float L[16][NCLS + 4];
  const int wave = threadIdx.x >> 6;
  const int lane = threadIdx.x & 63;
  const int l15 = lane & 15;
  const int quad = lane >> 4;

  B8 bfrag[8];
  const int n = wave * 16 + l15;
  const float bb = bl[n];
#pragma unroll
  for (int ks = 0; ks < 8; ++ks) {
    const float* wp = Wl + n * (2 * D) + ks * 32 + quad * 8;
    const float4 w0 = *reinterpret_cast<const float4*>(wp);
    const float4 w1 = *reinterpret_cast<const float4*>(wp + 4);
    B8 b;
    b.v[0] = (__bf16)w0.x; b.v[1] = (__bf16)w0.y; b.v[2] = (__bf16)w0.z; b.v[3] = (__bf16)w0.w;
    b.v[4] = (__bf16)w1.x; b.v[5] = (__bf16)w1.y; b.v[6] = (__bf16)w1.z; b.v[7] = (__bf16)w1.w;
    bfrag[ks] = b;
  }

  const int mtiles = N >> 4;
  for (int mt = blockIdx.x; mt < mtiles; mt += gridDim.x) {
    const size_t rb = (size_t)(mt * 16 + l15) * D + quad * 8;
    f32x4 acc = {0.f, 0.f, 0.f, 0.f};
    B8 a;
#pragma unroll
    for (int ks = 0; ks < 4; ++ks) {
      a.u = *reinterpret_cast<const uint4*>(H1 + rb + ks * 32);
      acc = __builtin_amdgcn_mfma_f32_16x16x32_bf16(a.v, bfrag[ks].v, acc, 0, 0, 0);
    }
#pragma unroll
    for (int ks = 0; ks < 4; ++ks) {
      a.u = *reinterpret_cast<const uint4*>(H2 + rb + ks * 32);
      acc = __builtin_amdgcn_mfma_f32_16x16x32_bf16(a.v, bfrag[4 + ks].v, acc, 0, 0, 0);
    }
#pragma unroll
    for (int r = 0; r < 4; ++r)
      L[quad * 4 + r][wave * 16 + l15] = acc[r] + bb;
    __syncthreads();
#pragma unroll
    for (int r = 0; r < 4; ++r) {
      const int row = wave * 4 + r;
      float v = L[row][lane];
      float m = v;
#pragma unroll
      for (int off = 32; off > 0; off >>= 1) m = fmaxf(m, __shfl_xor(m, off));
      float e = __expf(v - m);
#pragma unroll
      for (int off = 32; off > 0; off >>= 1) e += __shfl_xor(e, off);
      out[(size_t)(mt * 16 + row) * NCLS + lane] = v - m - __logf(e);
    }
    __syncthreads();
  }
}

// ---- driver --------------------------------------------------------------

extern "C" void kernel_launch(void* const* d_in, const int* in_sizes, int n_in,
                              void* d_out, int out_size, void* d_ws, size_t ws_size,
                              hipStream_t stream) {
  const float* feat = (const float*)d_in[0];
  const int* src = (const int*)d_in[1];
  const int* dst = (const int*)d_in[2];
  const float* W1 = (const float*)d_in[3];
  const float* b1 = (const float*)d_in[4];
  const float* W2 = (const float*)d_in[5];
  const float* b2 = (const float*)d_in[6];
  const float* Wl = (const float*)d_in[7];
  const float* bl = (const float*)d_in[8];
  float* out = (float*)d_out;

  const int N = in_sizes[0] / D;  // 100000
  const int E = in_sizes[1];      // 1600000

  // workspace layout
  float* ws = (float*)d_ws;
  float* inv = ws;                          // N f32
  ushort* featb = (ushort*)(inv + N);       // N*D bf16
  ushort* aggb = featb + (size_t)N * D;     // N*D
  ushort* h1b = aggb + (size_t)N * D;       // N*D
  ushort* h2b = h1b + (size_t)N * D;        // N*D
  int* cnt = (int*)(h2b + (size_t)N * D);   // N
  int* loc = cnt + N;                       // N
  int* part = loc + N;                      // 128
  int* row_ptr = part + 128;                // N+1
  int* cursor = row_ptr + N + 1;            // N
  int* esrc = cursor + N;                   // E

  const int scanBlocks = (N + 1023) / 1024;  // 98

  hipMemsetAsync(cnt, 0, (size_t)N * sizeof(int), stream);

  // bf16 copy of features
  const int n8 = N * D / 8;
  k_tobf16<<<(n8 + 255) / 256, 256, 0, stream>>>(feat, featb, n8);

  // CSR build
  k_hist<<<(E + 255) / 256, 256, 0, stream>>>(dst, cnt, E);
  k_invdeg<<<(N + 255) / 256, 256, 0, stream>>>(cnt, inv, N);
  k_scan1<<<scanBlocks, 256, 0, stream>>>(cnt, loc, part, N);
  k_scan2<<<1, 128, 0, stream>>>(part, scanBlocks);
  k_scan3<<<scanBlocks, 256, 0, stream>>>(loc, part, row_ptr, cursor, N, E);
  k_scatter<<<(E + 255) / 256, 256, 0, stream>>>(src, dst, cursor, esrc, E);

  const int gatherBlocks = (N + 3) / 4;

  // layer 1
  k_gather_mean<<<gatherBlocks, 256, 0, stream>>>(featb, row_ptr, esrc, inv, aggb, N);
  k_gemm_mfma<<<2048, 256, 0, stream>>>(aggb, W1, b1, h1b, N);

  // layer 2
  k_gather_mean<<<gatherBlocks, 256, 0, stream>>>(h1b, row_ptr, esrc, inv, aggb, N);
  k_gemm_mfma<<<2048, 256, 0, stream>>>(aggb, W2, b2, h2b, N);

  // logits + log_softmax
  k_logits_sm<<<1024, 256, 0, stream>>>(h1b, h2b, Wl, bl, out, N);
}

// Round 4
// 485.879 us; speedup vs baseline: 12.0222x; 1.2393x over previous
//
#include <hip/hip_runtime.h>
#include <stdint.h>

#define D 128
#define NCLS 64
#define BSH 7       // 128 nodes per bucket
#define NBMAX 1024  // max buckets (N <= 131072)
#define CCHUNK 4096 // edges per k_bscatter block

typedef __bf16 bf16x8 __attribute__((ext_vector_type(8)));
typedef float f32x4 __attribute__((ext_vector_type(4)));

union B8 { uint4 u; bf16x8 v; };

// ---- f32 -> bf16 bulk convert (8 elems/thread) ---------------------------

__global__ __launch_bounds__(256) void k_tobf16(const float* __restrict__ x,
                                                ushort* __restrict__ y, int n8) {
  int t = blockIdx.x * 256 + threadIdx.x;
  if (t >= n8) return;
  const float4 a = reinterpret_cast<const float4*>(x)[t * 2 + 0];
  const float4 b = reinterpret_cast<const float4*>(x)[t * 2 + 1];
  union { __bf16 h[8]; uint4 u; } p;
  p.h[0] = (__bf16)a.x; p.h[1] = (__bf16)a.y; p.h[2] = (__bf16)a.z; p.h[3] = (__bf16)a.w;
  p.h[4] = (__bf16)b.x; p.h[5] = (__bf16)b.y; p.h[6] = (__bf16)b.z; p.h[7] = (__bf16)b.w;
  reinterpret_cast<uint4*>(y)[t] = p.u;
}

// ---- bucketed CSR build --------------------------------------------------
// bucket b covers nodes [b*128, b*128+128); all heavy random traffic is LDS.

__global__ __launch_bounds__(256) void k_bhist(const int* __restrict__ dst,
                                               int* __restrict__ bcnt, int E, int NB) {
  __shared__ int h[NBMAX];
  for (int i = threadIdx.x; i < NB; i += 256) h[i] = 0;
  __syncthreads();
  for (int e = blockIdx.x * 256 + threadIdx.x; e < E; e += gridDim.x * 256)
    atomicAdd(&h[dst[e] >> BSH], 1);
  __syncthreads();
  for (int i = threadIdx.x; i < NB; i += 256) {
    int c = h[i];
    if (c) atomicAdd(&bcnt[i], c);
  }
}

__global__ __launch_bounds__(1024) void k_bscan(const int* __restrict__ bcnt,
                                                int* __restrict__ bbase,
                                                int* __restrict__ bcur, int NB, int E) {
  __shared__ int sm[NBMAX];
  const int tid = threadIdx.x;
  int v = (tid < NB) ? bcnt[tid] : 0;
  sm[tid] = v;
  __syncthreads();
  for (int off = 1; off < NBMAX; off <<= 1) {
    int t = (tid >= off) ? sm[tid - off] : 0;
    __syncthreads();
    sm[tid] += t;
    __syncthreads();
  }
  if (tid < NB) {
    bbase[tid] = sm[tid] - v;
    bcur[tid] = sm[tid] - v;
  }
  if (tid == 0) bbase[NB] = E;
}

// scatter packed (src<<7)|dstLow into bucket-grouped ebuck; per-block LDS
// count -> reserve range -> rank, so global atomics are <=NB per block.

__global__ __launch_bounds__(256) void k_bscatter(const int* __restrict__ src,
                                                  const int* __restrict__ dst,
                                                  int* __restrict__ bcur,
                                                  int* __restrict__ ebuck, int E, int NB) {
  __shared__ int h[NBMAX];
  __shared__ int base[NBMAX];
  const int beg = blockIdx.x * CCHUNK;
  const int end = min(beg + CCHUNK, E);
  for (int i = threadIdx.x; i < NB; i += 256) h[i] = 0;
  __syncthreads();
  for (int e = beg + threadIdx.x; e < end; e += 256)
    atomicAdd(&h[dst[e] >> BSH], 1);
  __syncthreads();
  for (int i = threadIdx.x; i < NB; i += 256) {
    int c = h[i];
    base[i] = c ? atomicAdd(&bcur[i], c) : 0;
    h[i] = 0;  // becomes local rank cursor
  }
  __syncthreads();
  for (int e = beg + threadIdx.x; e < end; e += 256) {
    const int d = dst[e];
    const int b = d >> BSH;
    const int r = atomicAdd(&h[b], 1);
    ebuck[base[b] + r] = (src[e] << BSH) | (d & 127);
  }
}

// one block per bucket: per-node counts/scan/row_ptr/inv + in-bucket scatter.
// esrc writes land in a ~8 KB contiguous window.

__global__ __launch_bounds__(256) void k_bbuild(const int* __restrict__ ebuck,
                                                const int* __restrict__ bbase,
                                                int* __restrict__ row_ptr,
                                                int* __restrict__ esrc,
                                                float* __restrict__ inv, int N, int E) {
  __shared__ int cnt[128], s[128], cur[128];
  const int b = blockIdx.x;
  const int n0 = b << BSH;
  const int nn = min(128, N - n0);
  const int beg = bbase[b], end = bbase[b + 1];
  const int tid = threadIdx.x;
  if (tid < 128) cnt[tid] = 0;
  __syncthreads();
  for (int e = beg + tid; e < end; e += 256)
    atomicAdd(&cnt[ebuck[e] & 127], 1);
  __syncthreads();
  if (tid < 128) s[tid] = cnt[tid];
  __syncthreads();
  for (int off = 1; off < 128; off <<= 1) {
    int t = (tid < 128 && tid >= off) ? s[tid - off] : 0;
    __syncthreads();
    if (tid < 128) s[tid] += t;
    __syncthreads();
  }
  if (tid < 128) {
    const int ex = s[tid] - cnt[tid];
    cur[tid] = ex;
    if (tid < nn) {
      row_ptr[n0 + tid] = beg + ex;
      inv[n0 + tid] = 1.0f / fmaxf((float)cnt[tid], 1.0f);
    }
  }
  if (b == 0 && tid == 0) row_ptr[N] = E;
  __syncthreads();
  for (int e = beg + tid; e < end; e += 256) {
    const int p = ebuck[e];
    const int r = atomicAdd(&cur[p & 127], 1);
    esrc[beg + r] = p >> BSH;
  }
}

// ---- mean aggregation via CSR gather: one wave per node, bf16 ------------

__global__ __launch_bounds__(256) void k_gather_mean(const ushort* __restrict__ h,
                                                     const int* __restrict__ row_ptr,
                                                     const int* __restrict__ esrc,
                                                     const float* __restrict__ inv,
                                                     ushort* __restrict__ out, int N) {
  const int node = blockIdx.x * 4 + (threadIdx.x >> 6);
  if (node >= N) return;
  const int lane = threadIdx.x & 63;
  const int beg = row_ptr[node];
  const int end = row_ptr[node + 1];
  float ax = 0.f, ay = 0.f;
  int e = beg;
  for (; e + 1 < end; e += 2) {
    const int s0 = esrc[e];
    const int s1 = esrc[e + 1];
    const unsigned int u0 = *reinterpret_cast<const unsigned int*>(h + (size_t)s0 * D + lane * 2);
    const unsigned int u1 = *reinterpret_cast<const unsigned int*>(h + (size_t)s1 * D + lane * 2);
    ax += __uint_as_float(u0 << 16) + __uint_as_float(u1 << 16);
    ay += __uint_as_float(u0 & 0xffff0000u) + __uint_as_float(u1 & 0xffff0000u);
  }
  if (e < end) {
    const unsigned int u0 = *reinterpret_cast<const unsigned int*>(h + (size_t)esrc[e] * D + lane * 2);
    ax += __uint_as_float(u0 << 16);
    ay += __uint_as_float(u0 & 0xffff0000u);
  }
  const float iv = inv[node];
  union { __bf16 b[2]; unsigned int u; } p;
  p.b[0] = (__bf16)(ax * iv);
  p.b[1] = (__bf16)(ay * iv);
  *reinterpret_cast<unsigned int*>(out + (size_t)node * D + lane * 2) = p.u;
}

// ---- MFMA GEMM: Hout = relu(A @ W^T + bias) ------------------------------

__global__ __launch_bounds__(256) void k_gemm_mfma(const ushort* __restrict__ A,
                                                   const float* __restrict__ W,
                                                   const float* __restrict__ bias,
                                                   ushort* __restrict__ Hout, int N) {
  const int wave = threadIdx.x >> 6;
  const int lane = threadIdx.x & 63;
  const int l15 = lane & 15;
  const int quad = lane >> 4;

  B8 bfrag[2][4];
  float bv[2];
#pragma unroll
  for (int t = 0; t < 2; ++t) {
    const int n = wave * 32 + t * 16 + l15;
    bv[t] = bias[n];
#pragma unroll
    for (int ks = 0; ks < 4; ++ks) {
      const float* wp = W + n * D + ks * 32 + quad * 8;
      const float4 w0 = *reinterpret_cast<const float4*>(wp);
      const float4 w1 = *reinterpret_cast<const float4*>(wp + 4);
      B8 b;
      b.v[0] = (__bf16)w0.x; b.v[1] = (__bf16)w0.y; b.v[2] = (__bf16)w0.z; b.v[3] = (__bf16)w0.w;
      b.v[4] = (__bf16)w1.x; b.v[5] = (__bf16)w1.y; b.v[6] = (__bf16)w1.z; b.v[7] = (__bf16)w1.w;
      bfrag[t][ks] = b;
    }
  }

  const int mtiles = N >> 4;
  for (int mt = blockIdx.x; mt < mtiles; mt += gridDim.x) {
    const ushort* ap = A + (size_t)(mt * 16 + l15) * D + quad * 8;
    B8 a0, a1, a2, a3;
    a0.u = *reinterpret_cast<const uint4*>(ap);
    a1.u = *reinterpret_cast<const uint4*>(ap + 32);
    a2.u = *reinterpret_cast<const uint4*>(ap + 64);
    a3.u = *reinterpret_cast<const uint4*>(ap + 96);
#pragma unroll
    for (int t = 0; t < 2; ++t) {
      f32x4 acc = {0.f, 0.f, 0.f, 0.f};
      acc = __builtin_amdgcn_mfma_f32_16x16x32_bf16(a0.v, bfrag[t][0].v, acc, 0, 0, 0);
      acc = __builtin_amdgcn_mfma_f32_16x16x32_bf16(a1.v, bfrag[t][1].v, acc, 0, 0, 0);
      acc = __builtin_amdgcn_mfma_f32_16x16x32_bf16(a2.v, bfrag[t][2].v, acc, 0, 0, 0);
      acc = __builtin_amdgcn_mfma_f32_16x16x32_bf16(a3.v, bfrag[t][3].v, acc, 0, 0, 0);
      const int col = wave * 32 + t * 16 + l15;
#pragma unroll
      for (int r = 0; r < 4; ++r) {
        const int row = mt * 16 + quad * 4 + r;
        const float v = fmaxf(acc[r] + bv[t], 0.f);
        union { __bf16 b; ushort s; } c;
        c.b = (__bf16)v;
        Hout[(size_t)row * D + col] = c.s;
      }
    }
  }
}

// ---- logits + log_softmax fused ------------------------------------------

__global__ __launch_bounds__(256) void k_logits_sm(const ushort* __restrict__ H1,
                                                   const ushort* __restrict__ H2,
                                                   const float* __restrict__ Wl,
                                                   const float* __restrict__ bl,
                                                   float* __restrict__ out, int N) {
  __shared__ float L[16][NCLS + 4];
  const int wave = threadIdx.x >> 6;
  const int lane = threadIdx.x & 63;
  const int l15 = lane & 15;
  const int quad = lane >> 4;

  B8 bfrag[8];
  const int n = wave * 16 + l15;
  const float bb = bl[n];
#pragma unroll
  for (int ks = 0; ks < 8; ++ks) {
    const float* wp = Wl + n * (2 * D) + ks * 32 + quad * 8;
    const float4 w0 = *reinterpret_cast<const float4*>(wp);
    const float4 w1 = *reinterpret_cast<const float4*>(wp + 4);
    B8 b;
    b.v[0] = (__bf16)w0.x; b.v[1] = (__bf16)w0.y; b.v[2] = (__bf16)w0.z; b.v[3] = (__bf16)w0.w;
    b.v[4] = (__bf16)w1.x; b.v[5] = (__bf16)w1.y; b.v[6] = (__bf16)w1.z; b.v[7] = (__bf16)w1.w;
    bfrag[ks] = b;
  }

  const int mtiles = N >> 4;
  for (int mt = blockIdx.x; mt < mtiles; mt += gridDim.x) {
    const size_t rb = (size_t)(mt * 16 + l15) * D + quad * 8;
    f32x4 acc = {0.f, 0.f, 0.f, 0.f};
    B8 a;
#pragma unroll
    for (int ks = 0; ks < 4; ++ks) {
      a.u = *reinterpret_cast<const uint4*>(H1 + rb + ks * 32);
      acc = __builtin_amdgcn_mfma_f32_16x16x32_bf16(a.v, bfrag[ks].v, acc, 0, 0, 0);
    }
#pragma unroll
    for (int ks = 0; ks < 4; ++ks) {
      a.u = *reinterpret_cast<const uint4*>(H2 + rb + ks * 32);
      acc = __builtin_amdgcn_mfma_f32_16x16x32_bf16(a.v, bfrag[4 + ks].v, acc, 0, 0, 0);
    }
#pragma unroll
    for (int r = 0; r < 4; ++r)
      L[quad * 4 + r][wave * 16 + l15] = acc[r] + bb;
    __syncthreads();
#pragma unroll
    for (int r = 0; r < 4; ++r) {
      const int row = wave * 4 + r;
      float v = L[row][lane];
      float m = v;
#pragma unroll
      for (int off = 32; off > 0; off >>= 1) m = fmaxf(m, __shfl_xor(m, off));
      float e = __expf(v - m);
#pragma unroll
      for (int off = 32; off > 0; off >>= 1) e += __shfl_xor(e, off);
      out[(size_t)(mt * 16 + row) * NCLS + lane] = v - m - __logf(e);
    }
    __syncthreads();
  }
}

// ---- driver --------------------------------------------------------------

extern "C" void kernel_launch(void* const* d_in, const int* in_sizes, int n_in,
                              void* d_out, int out_size, void* d_ws, size_t ws_size,
                              hipStream_t stream) {
  const float* feat = (const float*)d_in[0];
  const int* src = (const int*)d_in[1];
  const int* dst = (const int*)d_in[2];
  const float* W1 = (const float*)d_in[3];
  const float* b1 = (const float*)d_in[4];
  const float* W2 = (const float*)d_in[5];
  const float* b2 = (const float*)d_in[6];
  const float* Wl = (const float*)d_in[7];
  const float* bl = (const float*)d_in[8];
  float* out = (float*)d_out;

  const int N = in_sizes[0] / D;  // 100000
  const int E = in_sizes[1];      // 1600000
  const int NB = (N + 127) >> BSH;  // 782

  // workspace layout
  float* ws = (float*)d_ws;
  float* inv = ws;                          // N
  ushort* featb = (ushort*)(inv + N);       // N*D
  ushort* aggb = featb + (size_t)N * D;     // N*D (ebuck aliases this during build)
  ushort* h1b = aggb + (size_t)N * D;       // N*D
  ushort* h2b = h1b + (size_t)N * D;        // N*D
  int* row_ptr = (int*)(h2b + (size_t)N * D);  // N+1
  int* esrc = row_ptr + N + 1;              // E
  int* bcnt = esrc + E;                     // NBMAX
  int* bbase = bcnt + NBMAX;                // NBMAX+1
  int* bcur = bbase + NBMAX + 1;            // NBMAX
  int* ebuck = (int*)aggb;                  // E ints, reused before aggb is live

  hipMemsetAsync(bcnt, 0, NBMAX * sizeof(int), stream);

  // bf16 copy of features (independent of CSR build)
  const int n8 = N * D / 8;
  k_tobf16<<<(n8 + 255) / 256, 256, 0, stream>>>(feat, featb, n8);

  // bucketed CSR build
  k_bhist<<<256, 256, 0, stream>>>(dst, bcnt, E, NB);
  k_bscan<<<1, 1024, 0, stream>>>(bcnt, bbase, bcur, NB, E);
  k_bscatter<<<(E + CCHUNK - 1) / CCHUNK, 256, 0, stream>>>(src, dst, bcur, ebuck, E, NB);
  k_bbuild<<<NB, 256, 0, stream>>>(ebuck, bbase, row_ptr, esrc, inv, N, E);

  const int gatherBlocks = (N + 3) / 4;

  // layer 1
  k_gather_mean<<<gatherBlocks, 256, 0, stream>>>(featb, row_ptr, esrc, inv, aggb, N);
  k_gemm_mfma<<<2048, 256, 0, stream>>>(aggb, W1, b1, h1b, N);

  // layer 2
  k_gather_mean<<<gatherBlocks, 256, 0, stream>>>(h1b, row_ptr, esrc, inv, aggb, N);
  k_gemm_mfma<<<2048, 256, 0, stream>>>(aggb, W2, b2, h2b, N);

  // logits + log_softmax
  k_logits_sm<<<1024, 256, 0, stream>>>(h1b, h2b, Wl, bl, out, N);
}

// Round 5
// 419.122 us; speedup vs baseline: 13.9371x; 1.1593x over previous
//
#include <hip/hip_runtime.h>
#include <stdint.h>

#define D 128
#define NCLS 64
#define BSH 7       // 128 nodes per bucket
#define NBMAX 1024  // max buckets (N <= 131072)
#define CCHUNK 4096 // edges per k_bscatter block

typedef __bf16 bf16x8 __attribute__((ext_vector_type(8)));
typedef float f32x4 __attribute__((ext_vector_type(4)));

union B8 { uint4 u; bf16x8 v; };

// ---- f32 -> bf16 bulk convert (8 elems/thread) ---------------------------

__global__ __launch_bounds__(256) void k_tobf16(const float* __restrict__ x,
                                                ushort* __restrict__ y, int n8) {
  int t = blockIdx.x * 256 + threadIdx.x;
  if (t >= n8) return;
  const float4 a = reinterpret_cast<const float4*>(x)[t * 2 + 0];
  const float4 b = reinterpret_cast<const float4*>(x)[t * 2 + 1];
  union { __bf16 h[8]; uint4 u; } p;
  p.h[0] = (__bf16)a.x; p.h[1] = (__bf16)a.y; p.h[2] = (__bf16)a.z; p.h[3] = (__bf16)a.w;
  p.h[4] = (__bf16)b.x; p.h[5] = (__bf16)b.y; p.h[6] = (__bf16)b.z; p.h[7] = (__bf16)b.w;
  reinterpret_cast<uint4*>(y)[t] = p.u;
}

// ---- all three weight matrices -> bf16, one launch -----------------------

__global__ __launch_bounds__(256) void k_wprep(const float* __restrict__ W1,
                                               const float* __restrict__ W2,
                                               const float* __restrict__ Wl,
                                               ushort* __restrict__ W1b,
                                               ushort* __restrict__ W2b,
                                               ushort* __restrict__ Wlb) {
  const int n1 = D * D / 8;        // 2048 groups per 128x128
  const int nl = 2 * D * NCLS / 8; // 4096 groups for Wl
  int t = blockIdx.x * 256 + threadIdx.x;
  const float* xp; ushort* yp; int idx;
  if (t < n1) { xp = W1; yp = W1b; idx = t; }
  else if (t < 2 * n1) { xp = W2; yp = W2b; idx = t - n1; }
  else if (t < 2 * n1 + nl) { xp = Wl; yp = Wlb; idx = t - 2 * n1; }
  else return;
  const float4 a = reinterpret_cast<const float4*>(xp)[idx * 2 + 0];
  const float4 b = reinterpret_cast<const float4*>(xp)[idx * 2 + 1];
  union { __bf16 h[8]; uint4 u; } p;
  p.h[0] = (__bf16)a.x; p.h[1] = (__bf16)a.y; p.h[2] = (__bf16)a.z; p.h[3] = (__bf16)a.w;
  p.h[4] = (__bf16)b.x; p.h[5] = (__bf16)b.y; p.h[6] = (__bf16)b.z; p.h[7] = (__bf16)b.w;
  reinterpret_cast<uint4*>(yp)[idx] = p.u;
}

// ---- bucketed CSR build --------------------------------------------------

__global__ __launch_bounds__(256) void k_bhist(const int* __restrict__ dst,
                                               int* __restrict__ bcnt, int E, int NB) {
  __shared__ int h[NBMAX];
  for (int i = threadIdx.x; i < NB; i += 256) h[i] = 0;
  __syncthreads();
  for (int e = blockIdx.x * 256 + threadIdx.x; e < E; e += gridDim.x * 256)
    atomicAdd(&h[dst[e] >> BSH], 1);
  __syncthreads();
  for (int i = threadIdx.x; i < NB; i += 256) {
    int c = h[i];
    if (c) atomicAdd(&bcnt[i], c);
  }
}

__global__ __launch_bounds__(1024) void k_bscan(const int* __restrict__ bcnt,
                                                int* __restrict__ bbase,
                                                int* __restrict__ bcur, int NB, int E) {
  __shared__ int sm[NBMAX];
  const int tid = threadIdx.x;
  int v = (tid < NB) ? bcnt[tid] : 0;
  sm[tid] = v;
  __syncthreads();
  for (int off = 1; off < NBMAX; off <<= 1) {
    int t = (tid >= off) ? sm[tid - off] : 0;
    __syncthreads();
    sm[tid] += t;
    __syncthreads();
  }
  if (tid < NB) {
    bbase[tid] = sm[tid] - v;
    bcur[tid] = sm[tid] - v;
  }
  if (tid == 0) bbase[NB] = E;
}

__global__ __launch_bounds__(256) void k_bscatter(const int* __restrict__ src,
                                                  const int* __restrict__ dst,
                                                  int* __restrict__ bcur,
                                                  int* __restrict__ ebuck, int E, int NB) {
  __shared__ int h[NBMAX];
  __shared__ int base[NBMAX];
  const int beg = blockIdx.x * CCHUNK;
  const int end = min(beg + CCHUNK, E);
  for (int i = threadIdx.x; i < NB; i += 256) h[i] = 0;
  __syncthreads();
  for (int e = beg + threadIdx.x; e < end; e += 256)
    atomicAdd(&h[dst[e] >> BSH], 1);
  __syncthreads();
  for (int i = threadIdx.x; i < NB; i += 256) {
    int c = h[i];
    base[i] = c ? atomicAdd(&bcur[i], c) : 0;
    h[i] = 0;  // becomes local rank cursor
  }
  __syncthreads();
  for (int e = beg + threadIdx.x; e < end; e += 256) {
    const int d = dst[e];
    const int b = d >> BSH;
    const int r = atomicAdd(&h[b], 1);
    ebuck[base[b] + r] = (src[e] << BSH) | (d & 127);
  }
}

__global__ __launch_bounds__(256) void k_bbuild(const int* __restrict__ ebuck,
                                                const int* __restrict__ bbase,
                                                int* __restrict__ row_ptr,
                                                int* __restrict__ esrc,
                                                float* __restrict__ inv, int N, int E) {
  __shared__ int cnt[128], s[128], cur[128];
  const int b = blockIdx.x;
  const int n0 = b << BSH;
  const int nn = min(128, N - n0);
  const int beg = bbase[b], end = bbase[b + 1];
  const int tid = threadIdx.x;
  if (tid < 128) cnt[tid] = 0;
  __syncthreads();
  for (int e = beg + tid; e < end; e += 256)
    atomicAdd(&cnt[ebuck[e] & 127], 1);
  __syncthreads();
  if (tid < 128) s[tid] = cnt[tid];
  __syncthreads();
  for (int off = 1; off < 128; off <<= 1) {
    int t = (tid < 128 && tid >= off) ? s[tid - off] : 0;
    __syncthreads();
    if (tid < 128) s[tid] += t;
    __syncthreads();
  }
  if (tid < 128) {
    const int ex = s[tid] - cnt[tid];
    cur[tid] = ex;
    if (tid < nn) {
      row_ptr[n0 + tid] = beg + ex;
      inv[n0 + tid] = 1.0f / fmaxf((float)cnt[tid], 1.0f);
    }
  }
  if (b == 0 && tid == 0) row_ptr[N] = E;
  __syncthreads();
  for (int e = beg + tid; e < end; e += 256) {
    const int p = ebuck[e];
    const int r = atomicAdd(&cur[p & 127], 1);
    esrc[beg + r] = p >> BSH;
  }
}

// ---- mean aggregation via CSR gather: one wave per node, bf16 ------------
// unroll-4: 4 independent 256 B row-loads in flight per wave (latency hiding)

__global__ __launch_bounds__(256) void k_gather_mean(const ushort* __restrict__ h,
                                                     const int* __restrict__ row_ptr,
                                                     const int* __restrict__ esrc,
                                                     const float* __restrict__ inv,
                                                     ushort* __restrict__ out, int N) {
  const int node = blockIdx.x * 4 + (threadIdx.x >> 6);
  if (node >= N) return;
  const int lane = threadIdx.x & 63;
  const int beg = row_ptr[node];
  const int end = row_ptr[node + 1];
  const ushort* hp = h + lane * 2;
  float ax = 0.f, ay = 0.f, bx = 0.f, by = 0.f;
  int e = beg;
  for (; e + 3 < end; e += 4) {
    const int s0 = esrc[e + 0];
    const int s1 = esrc[e + 1];
    const int s2 = esrc[e + 2];
    const int s3 = esrc[e + 3];
    const unsigned int u0 = *reinterpret_cast<const unsigned int*>(hp + (size_t)s0 * D);
    const unsigned int u1 = *reinterpret_cast<const unsigned int*>(hp + (size_t)s1 * D);
    const unsigned int u2 = *reinterpret_cast<const unsigned int*>(hp + (size_t)s2 * D);
    const unsigned int u3 = *reinterpret_cast<const unsigned int*>(hp + (size_t)s3 * D);
    ax += __uint_as_float(u0 << 16) + __uint_as_float(u1 << 16);
    ay += __uint_as_float(u0 & 0xffff0000u) + __uint_as_float(u1 & 0xffff0000u);
    bx += __uint_as_float(u2 << 16) + __uint_as_float(u3 << 16);
    by += __uint_as_float(u2 & 0xffff0000u) + __uint_as_float(u3 & 0xffff0000u);
  }
  if (e + 1 < end) {
    const int s0 = esrc[e + 0];
    const int s1 = esrc[e + 1];
    const unsigned int u0 = *reinterpret_cast<const unsigned int*>(hp + (size_t)s0 * D);
    const unsigned int u1 = *reinterpret_cast<const unsigned int*>(hp + (size_t)s1 * D);
    ax += __uint_as_float(u0 << 16) + __uint_as_float(u1 << 16);
    ay += __uint_as_float(u0 & 0xffff0000u) + __uint_as_float(u1 & 0xffff0000u);
    e += 2;
  }
  if (e < end) {
    const unsigned int u0 = *reinterpret_cast<const unsigned int*>(hp + (size_t)esrc[e] * D);
    ax += __uint_as_float(u0 << 16);
    ay += __uint_as_float(u0 & 0xffff0000u);
  }
  ax += bx;
  ay += by;
  const float iv = inv[node];
  union { __bf16 b[2]; unsigned int u; } p;
  p.b[0] = (__bf16)(ax * iv);
  p.b[1] = (__bf16)(ay * iv);
  *reinterpret_cast<unsigned int*>(out + (size_t)node * D + lane * 2) = p.u;
}

// ---- MFMA GEMM: Hout = relu(A @ W^T + bias), W pre-converted bf16 [n][k] --

__global__ __launch_bounds__(256) void k_gemm_mfma(const ushort* __restrict__ A,
                                                   const ushort* __restrict__ Wb,
                                                   const float* __restrict__ bias,
                                                   ushort* __restrict__ Hout, int N) {
  const int wave = threadIdx.x >> 6;
  const int lane = threadIdx.x & 63;
  const int l15 = lane & 15;
  const int quad = lane >> 4;

  B8 bfrag[2][4];
  float bv[2];
#pragma unroll
  for (int t = 0; t < 2; ++t) {
    const int n = wave * 32 + t * 16 + l15;
    bv[t] = bias[n];
#pragma unroll
    for (int ks = 0; ks < 4; ++ks)
      bfrag[t][ks].u = *reinterpret_cast<const uint4*>(Wb + n * D + ks * 32 + quad * 8);
  }

  const int mtiles = N >> 4;
  for (int mt = blockIdx.x; mt < mtiles; mt += gridDim.x) {
    const ushort* ap = A + (size_t)(mt * 16 + l15) * D + quad * 8;
    B8 a0, a1, a2, a3;
    a0.u = *reinterpret_cast<const uint4*>(ap);
    a1.u = *reinterpret_cast<const uint4*>(ap + 32);
    a2.u = *reinterpret_cast<const uint4*>(ap + 64);
    a3.u = *reinterpret_cast<const uint4*>(ap + 96);
#pragma unroll
    for (int t = 0; t < 2; ++t) {
      f32x4 acc = {0.f, 0.f, 0.f, 0.f};
      acc = __builtin_amdgcn_mfma_f32_16x16x32_bf16(a0.v, bfrag[t][0].v, acc, 0, 0, 0);
      acc = __builtin_amdgcn_mfma_f32_16x16x32_bf16(a1.v, bfrag[t][1].v, acc, 0, 0, 0);
      acc = __builtin_amdgcn_mfma_f32_16x16x32_bf16(a2.v, bfrag[t][2].v, acc, 0, 0, 0);
      acc = __builtin_amdgcn_mfma_f32_16x16x32_bf16(a3.v, bfrag[t][3].v, acc, 0, 0, 0);
      const int col = wave * 32 + t * 16 + l15;
#pragma unroll
      for (int r = 0; r < 4; ++r) {
        const int row = mt * 16 + quad * 4 + r;
        const float v = fmaxf(acc[r] + bv[t], 0.f);
        union { __bf16 b; ushort s; } c;
        c.b = (__bf16)v;
        Hout[(size_t)row * D + col] = c.s;
      }
    }
  }
}

// ---- logits + log_softmax fused (Wl pre-converted bf16 [n][k]) -----------

__global__ __launch_bounds__(256) void k_logits_sm(const ushort* __restrict__ H1,
                                                   const ushort* __restrict__ H2,
                                                   const ushort* __restrict__ Wlb,
                                                   const float* __restrict__ bl,
                                                   float* __restrict__ out, int N) {
  __shared__ float L[16][NCLS + 4];
  const int wave = threadIdx.x >> 6;
  const int lane = threadIdx.x & 63;
  const int l15 = lane & 15;
  const int quad = lane >> 4;

  B8 bfrag[8];
  const int n = wave * 16 + l15;
  const float bb = bl[n];
#pragma unroll
  for (int ks = 0; ks < 8; ++ks)
    bfrag[ks].u = *reinterpret_cast<const uint4*>(Wlb + n * (2 * D) + ks * 32 + quad * 8);

  const int mtiles = N >> 4;
  for (int mt = blockIdx.x; mt < mtiles; mt += gridDim.x) {
    const size_t rb = (size_t)(mt * 16 + l15) * D + quad * 8;
    f32x4 acc = {0.f, 0.f, 0.f, 0.f};
    B8 a;
#pragma unroll
    for (int ks = 0; ks < 4; ++ks) {
      a.u = *reinterpret_cast<const uint4*>(H1 + rb + ks * 32);
      acc = __builtin_amdgcn_mfma_f32_16x16x32_bf16(a.v, bfrag[ks].v, acc, 0, 0, 0);
    }
#pragma unroll
    for (int ks = 0; ks < 4; ++ks) {
      a.u = *reinterpret_cast<const uint4*>(H2 + rb + ks * 32);
      acc = __builtin_amdgcn_mfma_f32_16x16x32_bf16(a.v, bfrag[4 + ks].v, acc, 0, 0, 0);
    }
#pragma unroll
    for (int r = 0; r < 4; ++r)
      L[quad * 4 + r][wave * 16 + l15] = acc[r] + bb;
    __syncthreads();
#pragma unroll
    for (int r = 0; r < 4; ++r) {
      const int row = wave * 4 + r;
      float v = L[row][lane];
      float m = v;
#pragma unroll
      for (int off = 32; off > 0; off >>= 1) m = fmaxf(m, __shfl_xor(m, off));
      float e = __expf(v - m);
#pragma unroll
      for (int off = 32; off > 0; off >>= 1) e += __shfl_xor(e, off);
      out[(size_t)(mt * 16 + row) * NCLS + lane] = v - m - __logf(e);
    }
    __syncthreads();
  }
}

// ---- driver --------------------------------------------------------------

extern "C" void kernel_launch(void* const* d_in, const int* in_sizes, int n_in,
                              void* d_out, int out_size, void* d_ws, size_t ws_size,
                              hipStream_t stream) {
  const float* feat = (const float*)d_in[0];
  const int* src = (const int*)d_in[1];
  const int* dst = (const int*)d_in[2];
  const float* W1 = (const float*)d_in[3];
  const float* b1 = (const float*)d_in[4];
  const float* W2 = (const float*)d_in[5];
  const float* b2 = (const float*)d_in[6];
  const float* Wl = (const float*)d_in[7];
  const float* bl = (const float*)d_in[8];
  float* out = (float*)d_out;

  const int N = in_sizes[0] / D;  // 100000
  const int E = in_sizes[1];      // 1600000
  const int NB = (N + 127) >> BSH;  // 782

  // workspace layout
  float* ws = (float*)d_ws;
  float* inv = ws;                          // N
  ushort* featb = (ushort*)(inv + N);       // N*D
  ushort* aggb = featb + (size_t)N * D;     // N*D (ebuck aliases this during build)
  ushort* h1b = aggb + (size_t)N * D;       // N*D
  ushort* h2b = h1b + (size_t)N * D;        // N*D
  int* row_ptr = (int*)(h2b + (size_t)N * D);  // N+1
  int* esrc = row_ptr + N + 1;              // E
  int* bcnt = esrc + E;                     // NBMAX
  int* bbase = bcnt + NBMAX;                // NBMAX+1
  int* bcur = bbase + NBMAX + 1;            // NBMAX
  ushort* W1b = (ushort*)(bcur + NBMAX);    // D*D
  ushort* W2b = W1b + D * D;                // D*D
  ushort* Wlb = W2b + D * D;                // 2*D*NCLS
  int* ebuck = (int*)aggb;                  // E ints, reused before aggb is live

  hipMemsetAsync(bcnt, 0, NBMAX * sizeof(int), stream);

  // bf16 copies: features + weights
  const int n8 = N * D / 8;
  k_tobf16<<<(n8 + 255) / 256, 256, 0, stream>>>(feat, featb, n8);
  k_wprep<<<(2 * D * D / 8 + 2 * D * NCLS / 8 + 255) / 256, 256, 0, stream>>>(
      W1, W2, Wl, W1b, W2b, Wlb);

  // bucketed CSR build
  k_bhist<<<256, 256, 0, stream>>>(dst, bcnt, E, NB);
  k_bscan<<<1, 1024, 0, stream>>>(bcnt, bbase, bcur, NB, E);
  k_bscatter<<<(E + CCHUNK - 1) / CCHUNK, 256, 0, stream>>>(src, dst, bcur, ebuck, E, NB);
  k_bbuild<<<NB, 256, 0, stream>>>(ebuck, bbase, row_ptr, esrc, inv, N, E);

  const int gatherBlocks = (N + 3) / 4;

  // layer 1
  k_gather_mean<<<gatherBlocks, 256, 0, stream>>>(featb, row_ptr, esrc, inv, aggb, N);
  k_gemm_mfma<<<2048, 256, 0, stream>>>(aggb, W1b, b1, h1b, N);

  // layer 2
  k_gather_mean<<<gatherBlocks, 256, 0, stream>>>(h1b, row_ptr, esrc, inv, aggb, N);
  k_gemm_mfma<<<2048, 256, 0, stream>>>(aggb, W2b, b2, h2b, N);

  // logits + log_softmax
  k_logits_sm<<<1024, 256, 0, stream>>>(h1b, h2b, Wlb, bl, out, N);
}